// Round 1
// baseline (41.863 us; speedup 1.0000x reference)
//
#include <hip/hip_runtime.h>

#define BATCH 128
#define LEN 512
#define NCHUNK 4
#define CH_STEPS 128          // ceil(511 / 4)
#define STEPS_TOTAL 511
#define SIG_DIM 4680          // 8 + 64 + 512 + 4096
#define N_OUT 10
#define OFF2 8
#define OFF3 72
#define OFF4 584

// ---------------------------------------------------------------------------
// Kernel 1: per-(batch, chunk) depth-4 signature of a sub-path via Chen scan.
// 512 threads; thread t owns (i,j,k) = (t>>6, (t>>3)&7, t&7):
//   s4[i][j][k][0..7] (8 regs), s3[i][j][k] (1 reg),
//   private copies of s2[i][j], s1[i]  -> no barriers in the step loop.
// ---------------------------------------------------------------------------
__global__ __launch_bounds__(512) void sig_chunk_kernel(const float* __restrict__ X,
                                                        float* __restrict__ ws) {
    const int wg = blockIdx.x;          // b * NCHUNK + ch
    const int b  = wg >> 2;
    const int ch = wg & 3;
    const int s0 = ch * CH_STEPS;
    const int nst = min(CH_STEPS, STEPS_TOTAL - s0);
    const int t = threadIdx.x;

    __shared__ __align__(16) float dx[CH_STEPS * 8];
    const float* __restrict__ Xb = X + (size_t)b * LEN * 8 + (size_t)s0 * 8;
    for (int idx = t; idx < nst * 8; idx += 512)
        dx[idx] = Xb[idx + 8] - Xb[idx];
    __syncthreads();

    const int i = t >> 6, j = (t >> 3) & 7, k = t & 7;
    float s1v = 0.f, s2v = 0.f, s3v = 0.f;
    float s4v[8] = {0.f, 0.f, 0.f, 0.f, 0.f, 0.f, 0.f, 0.f};

    #pragma unroll 4
    for (int s = 0; s < nst; ++s) {
        const float4 va = *(const float4*)&dx[s * 8];
        const float4 vb = *(const float4*)&dx[s * 8 + 4];
        const float vi = dx[s * 8 + i];   // wave-uniform broadcast
        const float vj = dx[s * 8 + j];
        const float vk = dx[s * 8 + k];

        // level-4: s4[l] += c0 * v[l],
        // c0 = s3 + s2*vk/2 + s1*vj*vk/6 + vi*vj*vk/24
        const float cin = fmaf(vj, fmaf(0.25f, vi, s1v) * (1.f / 3.f), s2v);
        const float c0  = fmaf(0.5f * vk, cin, s3v);
        s4v[0] = fmaf(c0, va.x, s4v[0]);
        s4v[1] = fmaf(c0, va.y, s4v[1]);
        s4v[2] = fmaf(c0, va.z, s4v[2]);
        s4v[3] = fmaf(c0, va.w, s4v[3]);
        s4v[4] = fmaf(c0, vb.x, s4v[4]);
        s4v[5] = fmaf(c0, vb.y, s4v[5]);
        s4v[6] = fmaf(c0, vb.z, s4v[6]);
        s4v[7] = fmaf(c0, vb.w, s4v[7]);

        // level-3: s3 += (s2 + s1*vj/2 + vi*vj/6) * vk
        const float qv = fmaf(0.5f * vj, fmaf(1.f / 3.f, vi, s1v), s2v);
        s3v = fmaf(qv, vk, s3v);

        // level-2: s2 += (s1 + vi/2) * vj
        s2v = fmaf(fmaf(0.5f, vi, s1v), vj, s2v);

        // level-1
        s1v += vi;
    }

    float* __restrict__ o = ws + (size_t)wg * SIG_DIM;
    if ((t & 63) == 0) o[t >> 6] = s1v;                // s1[i], thread t = 64*i
    if ((t & 7) == 0)  o[OFF2 + (t >> 3)] = s2v;       // s2[ij], thread k==0
    o[OFF3 + t] = s3v;
    *(float4*)&o[OFF4 + t * 8]     = make_float4(s4v[0], s4v[1], s4v[2], s4v[3]);
    *(float4*)&o[OFF4 + t * 8 + 4] = make_float4(s4v[4], s4v[5], s4v[6], s4v[7]);
}

// ---------------------------------------------------------------------------
// Kernel 2: per-batch Chen-combine of the NCHUNK chunk signatures + fused
// linear layer (sig @ W.T + b) with block reduction.
// ---------------------------------------------------------------------------
__global__ __launch_bounds__(512) void sig_combine_linear(const float* __restrict__ ws,
                                                          const float* __restrict__ W,
                                                          const float* __restrict__ bias,
                                                          float* __restrict__ out) {
    const int b = blockIdx.x;
    const int t = threadIdx.x;
    const int i = t >> 6, j = (t >> 3) & 7, k = t & 7;
    const float* __restrict__ base = ws + (size_t)b * NCHUNK * SIG_DIM;

    // A := chunk 0 signature (per-thread ownership as in kernel 1)
    float A1 = base[i];
    float A2 = base[OFF2 + i * 8 + j];
    float A3 = base[OFF3 + t];
    const float4 a4a = *(const float4*)&base[OFF4 + t * 8];
    const float4 a4b = *(const float4*)&base[OFF4 + t * 8 + 4];
    float A4[8] = {a4a.x, a4a.y, a4a.z, a4a.w, a4b.x, a4b.y, a4b.z, a4b.w};

    __shared__ __align__(16) float Bs[SIG_DIM];

    for (int c = 1; c < NCHUNK; ++c) {
        __syncthreads();                    // previous combine done reading Bs
        const float* __restrict__ cp = base + (size_t)c * SIG_DIM;
        for (int idx = t; idx < SIG_DIM; idx += 512) Bs[idx] = cp[idx];
        __syncthreads();

        const float B1i = Bs[i], B1j = Bs[j], B1k = Bs[k];
        const float4 b1a = *(const float4*)&Bs[0];
        const float4 b1b = *(const float4*)&Bs[4];
        const float B2ij = Bs[OFF2 + i * 8 + j];
        const float B2jk = Bs[OFF2 + j * 8 + k];
        const float4 b2a = *(const float4*)&Bs[OFF2 + k * 8];
        const float4 b2b = *(const float4*)&Bs[OFF2 + k * 8 + 4];
        const float B3ijk = Bs[OFF3 + t];
        const float4 b3a = *(const float4*)&Bs[OFF3 + (j * 8 + k) * 8];
        const float4 b3b = *(const float4*)&Bs[OFF3 + (j * 8 + k) * 8 + 4];
        const float4 b4a = *(const float4*)&Bs[OFF4 + t * 8];
        const float4 b4b = *(const float4*)&Bs[OFF4 + t * 8 + 4];

        // C4 = A4 + A3⊗B1 + A2⊗B2 + A1⊗B3 + B4   (old A1..A3)
        A4[0] += A3 * b1a.x + A2 * b2a.x + A1 * b3a.x + b4a.x;
        A4[1] += A3 * b1a.y + A2 * b2a.y + A1 * b3a.y + b4a.y;
        A4[2] += A3 * b1a.z + A2 * b2a.z + A1 * b3a.z + b4a.z;
        A4[3] += A3 * b1a.w + A2 * b2a.w + A1 * b3a.w + b4a.w;
        A4[4] += A3 * b1b.x + A2 * b2b.x + A1 * b3b.x + b4b.x;
        A4[5] += A3 * b1b.y + A2 * b2b.y + A1 * b3b.y + b4b.y;
        A4[6] += A3 * b1b.z + A2 * b2b.z + A1 * b3b.z + b4b.z;
        A4[7] += A3 * b1b.w + A2 * b2b.w + A1 * b3b.w + b4b.w;
        // C3 = A3 + A2⊗B1 + A1⊗B2 + B3
        A3 += A2 * B1k + A1 * B2jk + B3ijk;
        // C2 = A2 + A1⊗B1 + B2
        A2 += A1 * B1j + B2ij;
        // C1
        A1 += B1i;
    }

    // Fused linear: out[b][n] = sum_d sig[d] * W[n][d] + bias[n]
    float part[N_OUT];
    #pragma unroll
    for (int n = 0; n < N_OUT; ++n) {
        const float* __restrict__ Wn = W + (size_t)n * SIG_DIM;
        float p = A3 * Wn[OFF3 + t];
        const float4 w4a = *(const float4*)&Wn[OFF4 + t * 8];
        const float4 w4b = *(const float4*)&Wn[OFF4 + t * 8 + 4];
        p = fmaf(A4[0], w4a.x, p);
        p = fmaf(A4[1], w4a.y, p);
        p = fmaf(A4[2], w4a.z, p);
        p = fmaf(A4[3], w4a.w, p);
        p = fmaf(A4[4], w4b.x, p);
        p = fmaf(A4[5], w4b.y, p);
        p = fmaf(A4[6], w4b.z, p);
        p = fmaf(A4[7], w4b.w, p);
        if ((t & 7) == 0)  p = fmaf(A2, Wn[OFF2 + (t >> 3)], p);  // canonical s2 owner
        if ((t & 63) == 0) p = fmaf(A1, Wn[t >> 6], p);           // canonical s1 owner
        part[n] = p;
    }

    // wave reduce (64 lanes) then cross-wave via LDS
    #pragma unroll
    for (int n = 0; n < N_OUT; ++n) {
        #pragma unroll
        for (int off = 32; off > 0; off >>= 1)
            part[n] += __shfl_xor(part[n], off, 64);
    }
    __shared__ float red[8][N_OUT];
    const int wv = t >> 6, ln = t & 63;
    if (ln == 0) {
        #pragma unroll
        for (int n = 0; n < N_OUT; ++n) red[wv][n] = part[n];
    }
    __syncthreads();
    if (t < N_OUT) {
        float s = bias[t];
        #pragma unroll
        for (int w = 0; w < 8; ++w) s += red[w][t];
        out[b * N_OUT + t] = s;
    }
}

extern "C" void kernel_launch(void* const* d_in, const int* in_sizes, int n_in,
                              void* d_out, int out_size, void* d_ws, size_t ws_size,
                              hipStream_t stream) {
    const float* X    = (const float*)d_in[0];
    const float* W    = (const float*)d_in[1];
    const float* bias = (const float*)d_in[2];
    float* out = (float*)d_out;
    float* ws  = (float*)d_ws;   // uses NCHUNK*BATCH*SIG_DIM*4 = ~9.6 MB

    hipLaunchKernelGGL(sig_chunk_kernel, dim3(BATCH * NCHUNK), dim3(512), 0, stream, X, ws);
    hipLaunchKernelGGL(sig_combine_linear, dim3(BATCH), dim3(512), 0, stream, ws, W, bias, out);
}